// Round 12
// baseline (67.445 us; speedup 1.0000x reference)
//
#include <hip/hip_runtime.h>

#define NPIX 9216          // C*H*W = 1*96*96
#define NROWS (NPIX + 1)   // 9217 rows in zonotope
#define ROW4 (NPIX / 4)    // 2304 f32x4 per row
#define EPSV 0.1f

#define FILLB (NPIX * 9 / 4)   // 20736 fill blocks of 1024 threads, 1 store each

typedef float f32x4 __attribute__((ext_vector_type(4)));

// ---------------------------------------------------------------------------
// Kernel 1: zero-fill rows 1..9216 + bias row 0. One f32x4 store per thread.
// Blocks 0..20735 (1024 thr): single zero store, linear sweep (R9/R11's
// proven pattern, 4x fewer WG dispatches). Blocks 20736..20738: bias row.
// ---------------------------------------------------------------------------
__global__ __launch_bounds__(1024) void fill_kernel(const float* __restrict__ x,
                                                    f32x4* __restrict__ out) {
    const int bid = blockIdx.x;
    const int tid = threadIdx.x;
    if (bid < FILLB) {
        const f32x4 z = {0.0f, 0.0f, 0.0f, 0.0f};
        out[ROW4 + (long long)bid * 1024 + tid] = z;
    } else {
        const int c4 = (bid - FILLB) * 1024 + tid;   // 0 .. 3071, row-0 f32x4 idx
        if (c4 < ROW4) {
            const f32x4 xv = reinterpret_cast<const f32x4*>(x)[c4];
            f32x4 o;
#pragma unroll
            for (int d = 0; d < 4; ++d) {
                const float v = xv[d];
                o[d] = v + fmaxf(EPSV - v, 0.0f) * 0.5f
                         - fmaxf(v - (1.0f - EPSV), 0.0f) * 0.5f;
            }
            out[c4] = o;
        }
    }
}

// ---------------------------------------------------------------------------
// Kernel 2 (after fill): single block, 1024 threads. Scan + scatter only:
//  - per-pixel err + cond, block-wide shuffle scan (stream compaction)
//  - scatter: out[slot*NPIX + pixel] = err  (~3.7K dword stores)
// Rows past the compacted count keep the fill's zeros.
// ---------------------------------------------------------------------------
__global__ __launch_bounds__(1024) void finish_kernel(const float* __restrict__ x,
                                                      float* __restrict__ out) {
    __shared__ int wsum[16];
    const int tid  = threadIdx.x;
    const int lane = tid & 63;
    const int wid  = tid >> 6;
    const int base = tid * 9;      // 9 contiguous pixels per thread

    float e_loc[9];
    int   c_loc[9];
    int   cnt = 0;
#pragma unroll
    for (int k = 0; k < 9; ++k) {
        const float xv     = x[base + k];
        const float r_low  = fmaxf(EPSV - xv, 0.0f) * 0.5f;
        const float r_high = fmaxf(xv - (1.0f - EPSV), 0.0f) * 0.5f;
        const float e      = EPSV - r_low - r_high;
        e_loc[k] = e;
        c_loc[k] = (e >= 0.0f) ? 1 : 0;
        cnt += c_loc[k];
    }

    // inclusive shuffle scan of per-thread counts within each wave
    int v = cnt;
#pragma unroll
    for (int off = 1; off < 64; off <<= 1) {
        const int t = __shfl_up(v, off, 64);
        if (lane >= off) v += t;
    }
    if (lane == 63) wsum[wid] = v;
    __syncthreads();

    int woff = 0;
#pragma unroll
    for (int w = 0; w < 16; ++w) woff += (w < wid) ? wsum[w] : 0;

    int slot = woff + v - cnt;     // exclusive prefix (0-based)
#pragma unroll
    for (int k = 0; k < 9; ++k) {
        if (c_loc[k]) {
            ++slot;                // 1-based compacted slot == output row
            out[(long long)slot * NPIX + (base + k)] = e_loc[k];
        }
    }
}

extern "C" void kernel_launch(void* const* d_in, const int* in_sizes, int n_in,
                              void* d_out, int out_size, void* d_ws, size_t ws_size,
                              hipStream_t stream) {
    const float* x = (const float*)d_in[0];
    float* out = (float*)d_out;

    fill_kernel<<<FILLB + 3, 1024, 0, stream>>>(x, (f32x4*)out);
    finish_kernel<<<1, 1024, 0, stream>>>(x, out);
}